// Round 1
// baseline (1483.727 us; speedup 1.0000x reference)
//
#include <hip/hip_runtime.h>
#include <cstddef>

typedef _Float16 f16x8 __attribute__((ext_vector_type(8)));
typedef float f32x4 __attribute__((ext_vector_type(4)));

#define B_ 8
#define C_ 1024
#define T_ 8
#define H_ 28
#define W_ 28
#define E_ 512
#define N_ (T_*H_*W_)          // 6272
#define M_ (T_*(H_/2)*(W_/2))  // 1568

// ---------------------------------------------------------------------------
// prep: convert weights fp32->f16, fold BN + b_out into scale/shift
// ---------------------------------------------------------------------------
__global__ void prep_kernel(const float* __restrict__ wt, const float* __restrict__ wp,
                            const float* __restrict__ wg, const float* __restrict__ wo,
                            const float* __restrict__ b_out,
                            const float* __restrict__ gamma, const float* __restrict__ beta,
                            const float* __restrict__ mean, const float* __restrict__ var,
                            _Float16* __restrict__ wt_h, _Float16* __restrict__ wp_h,
                            _Float16* __restrict__ wg_h, _Float16* __restrict__ wo_h,
                            float* __restrict__ scale, float* __restrict__ shift,
                            int nW, int nC)
{
    int i = blockIdx.x * blockDim.x + threadIdx.x;
    if (i < nW) {
        wt_h[i] = (_Float16)wt[i];
        wp_h[i] = (_Float16)wp[i];
        wg_h[i] = (_Float16)wg[i];
        wo_h[i] = (_Float16)wo[i];
    }
    if (i < nC) {
        float sc = gamma[i] * rsqrtf(var[i] + 1e-5f);
        scale[i] = sc;
        shift[i] = (b_out[i] - mean[i]) * sc + beta[i];
    }
}

// ---------------------------------------------------------------------------
// XT[b][n][c] = (f16) x[b][c][n]   (32x32 LDS tile transpose)
// ---------------------------------------------------------------------------
__global__ void xt_kernel(const float* __restrict__ x, _Float16* __restrict__ XT)
{
    __shared__ float sm[32][33];
    int n0 = blockIdx.x * 32, c0 = blockIdx.y * 32, b = blockIdx.z;
    const float* xb = x + (size_t)b * C_ * N_;
    _Float16* xtb = XT + (size_t)b * N_ * C_;
#pragma unroll
    for (int i = 0; i < 4; i++) {
        int c = c0 + threadIdx.y + i * 8;
        sm[threadIdx.y + i * 8][threadIdx.x] = xb[(size_t)c * N_ + n0 + threadIdx.x];
    }
    __syncthreads();
#pragma unroll
    for (int i = 0; i < 4; i++) {
        int n = n0 + threadIdx.y + i * 8;
        xtb[(size_t)n * C_ + c0 + threadIdx.x] = (_Float16)sm[threadIdx.x][threadIdx.y + i * 8];
    }
}

// ---------------------------------------------------------------------------
// XST[b][m][c] = (f16) maxpool_122(x)[b][c][m]
// ---------------------------------------------------------------------------
__global__ void pool_kernel(const float* __restrict__ x, _Float16* __restrict__ XST)
{
    __shared__ float sm[32][33];
    const int H2 = H_ / 2, W2 = W_ / 2, HW = H_ * W_;
    int m0 = blockIdx.x * 32, c0 = blockIdx.y * 32, b = blockIdx.z;
    const float* xb = x + (size_t)b * C_ * T_ * HW;
#pragma unroll
    for (int i = 0; i < 4; i++) {
        int c = c0 + threadIdx.y + i * 8;
        int m = m0 + threadIdx.x;
        int t = m / (H2 * W2);
        int r = m - t * (H2 * W2);
        int h2 = r / W2;
        int w2 = r - h2 * W2;
        const float* p = xb + ((size_t)c * T_ + t) * HW + (h2 * 2) * W_ + w2 * 2;
        float v0 = fmaxf(p[0], p[1]);
        float v1 = fmaxf(p[W_], p[W_ + 1]);
        sm[threadIdx.y + i * 8][threadIdx.x] = fmaxf(v0, v1);
    }
    __syncthreads();
#pragma unroll
    for (int i = 0; i < 4; i++) {
        int m = m0 + threadIdx.y + i * 8;
        XST[((size_t)b * M_ + m) * C_ + c0 + threadIdx.x] = (_Float16)sm[threadIdx.x][threadIdx.y + i * 8];
    }
}

// ---------------------------------------------------------------------------
// softmax over rows of S [Nr x Md] fp32 -> P f16. One wave per row.
// ---------------------------------------------------------------------------
__global__ void softmax_kernel(const float* __restrict__ S, _Float16* __restrict__ P,
                               int Nr, int Md)
{
    int wave = threadIdx.x >> 6, lane = threadIdx.x & 63;
    int row = blockIdx.x * 4 + wave;
    if (row >= Nr) return;
    const float* s = S + (size_t)row * Md;
    float vals[25];
    float mx = -3.4e38f;
#pragma unroll
    for (int i = 0; i < 25; i++) {
        int idx = lane + i * 64;
        float v = (idx < Md) ? s[idx] : -3.4e38f;
        vals[i] = v;
        mx = fmaxf(mx, v);
    }
#pragma unroll
    for (int off = 32; off > 0; off >>= 1) mx = fmaxf(mx, __shfl_xor(mx, off, 64));
    float sum = 0.f;
#pragma unroll
    for (int i = 0; i < 25; i++) {
        int idx = lane + i * 64;
        float e = (idx < Md) ? __expf(vals[i] - mx) : 0.f;
        vals[i] = e;
        sum += e;
    }
#pragma unroll
    for (int off = 32; off > 0; off >>= 1) sum += __shfl_xor(sum, off, 64);
    float inv = 1.f / sum;
    _Float16* p = P + (size_t)row * Md;
#pragma unroll
    for (int i = 0; i < 25; i++) {
        int idx = lane + i * 64;
        if (idx < Md) p[idx] = (_Float16)(vals[i] * inv);
    }
}

// ---------------------------------------------------------------------------
// Generic NT GEMM: C[m,n] = sum_k A[m,k]*B[n,k]  (A:[Mdim,K] rm, B:[Ndim,K] rm)
// 128x128 tile, BK=32, 4 waves (2x2 of 64x64), mfma f32_16x16x32_f16.
// BIAS: 0 none, 1 per-col, 2 per-row
// EPI : 0 store f16, 1 store f32, 2 fused BN+residual store f32
// ---------------------------------------------------------------------------
template<int BIAS, int EPI>
__global__ __launch_bounds__(256, 2)
void gemm_nt(const _Float16* __restrict__ A, const _Float16* __restrict__ B,
             void* __restrict__ Cout, const float* __restrict__ bias,
             const float* __restrict__ scale, const float* __restrict__ shift,
             const float* __restrict__ resid,
             int Mdim, int Ndim, int K,
             long long strideA, long long strideB, long long strideC)
{
    constexpr int PAD = 40;  // 32 + 8 halves: keeps 16B alignment, breaks bank conflicts
    __shared__ alignas(16) _Float16 As[128 * PAD];
    __shared__ alignas(16) _Float16 Bs[128 * PAD];

    const int tid = threadIdx.x;
    const int lane = tid & 63;
    const int wave = tid >> 6;
    const int wm = wave >> 1, wn = wave & 1;
    const int lane15 = lane & 15, quad = lane >> 4;

    const int m0 = blockIdx.y * 128;
    const int n0 = blockIdx.x * 128;
    const int bz = blockIdx.z;
    A += (size_t)bz * strideA;
    B += (size_t)bz * strideB;

    const int srow = tid >> 1;          // 0..127
    const int koff = (tid & 1) * 16;    // 0 / 16
    const int arow = m0 + srow;
    const int brow = n0 + srow;
    const bool aval = arow < Mdim;
    const bool bval = brow < Ndim;
    const _Float16* aptr = A + (size_t)arow * K + koff;
    const _Float16* bptr = B + (size_t)brow * K + koff;

    f32x4 acc[4][4];
#pragma unroll
    for (int i = 0; i < 4; i++)
#pragma unroll
        for (int j = 0; j < 4; j++)
            acc[i][j] = (f32x4){0.f, 0.f, 0.f, 0.f};

    f16x8 z8;
#pragma unroll
    for (int q = 0; q < 8; q++) z8[q] = (_Float16)0.f;

    for (int k0 = 0; k0 < K; k0 += 32) {
        f16x8 av0 = z8, av1 = z8, bv0 = z8, bv1 = z8;
        if (aval) {
            av0 = *(const f16x8*)(aptr + k0);
            av1 = *(const f16x8*)(aptr + k0 + 8);
        }
        if (bval) {
            bv0 = *(const f16x8*)(bptr + k0);
            bv1 = *(const f16x8*)(bptr + k0 + 8);
        }
        __syncthreads();
        *(f16x8*)&As[srow * PAD + koff] = av0;
        *(f16x8*)&As[srow * PAD + koff + 8] = av1;
        *(f16x8*)&Bs[srow * PAD + koff] = bv0;
        *(f16x8*)&Bs[srow * PAD + koff + 8] = bv1;
        __syncthreads();

        f16x8 af[4], bf[4];
#pragma unroll
        for (int i = 0; i < 4; i++)
            af[i] = *(const f16x8*)&As[(wm * 64 + i * 16 + lane15) * PAD + quad * 8];
#pragma unroll
        for (int j = 0; j < 4; j++)
            bf[j] = *(const f16x8*)&Bs[(wn * 64 + j * 16 + lane15) * PAD + quad * 8];
#pragma unroll
        for (int i = 0; i < 4; i++)
#pragma unroll
            for (int j = 0; j < 4; j++)
                acc[i][j] = __builtin_amdgcn_mfma_f32_16x16x32_f16(af[i], bf[j], acc[i][j], 0, 0, 0);
    }

    // epilogue: D layout col=lane&15, row=quad*4+reg
    const size_t cbase = (size_t)bz * strideC;
#pragma unroll
    for (int i = 0; i < 4; i++) {
#pragma unroll
        for (int j = 0; j < 4; j++) {
            f32x4 v = acc[i][j];
            int gc = n0 + wn * 64 + j * 16 + lane15;
            if (gc >= Ndim) continue;
            float bcol = (BIAS == 1) ? bias[gc] : 0.f;
#pragma unroll
            for (int r = 0; r < 4; r++) {
                int gr = m0 + wm * 64 + i * 16 + quad * 4 + r;
                if (gr >= Mdim) continue;
                float val = v[r];
                if (BIAS == 1) val += bcol;
                if (BIAS == 2) val += bias[gr];
                size_t idx = cbase + (size_t)gr * Ndim + gc;
                if (EPI == 0) {
                    ((_Float16*)Cout)[idx] = (_Float16)val;
                } else if (EPI == 1) {
                    ((float*)Cout)[idx] = val;
                } else {
                    ((float*)Cout)[idx] = val * scale[gr] + shift[gr] + resid[idx];
                }
            }
        }
    }
}

// ---------------------------------------------------------------------------
extern "C" void kernel_launch(void* const* d_in, const int* in_sizes, int n_in,
                              void* d_out, int out_size, void* d_ws, size_t ws_size,
                              hipStream_t stream)
{
    const float* x       = (const float*)d_in[0];
    const float* w_theta = (const float*)d_in[1];
    const float* b_theta = (const float*)d_in[2];
    const float* w_phi   = (const float*)d_in[3];
    const float* b_phi   = (const float*)d_in[4];
    const float* w_g     = (const float*)d_in[5];
    const float* b_g     = (const float*)d_in[6];
    const float* w_out   = (const float*)d_in[7];
    const float* b_out   = (const float*)d_in[8];
    const float* gamma   = (const float*)d_in[9];
    const float* beta    = (const float*)d_in[10];
    const float* mean    = (const float*)d_in[11];
    const float* var     = (const float*)d_in[12];
    float* out = (float*)d_out;

    char* ws = (char*)d_ws;
    size_t off = 0;
    auto alloc = [&](size_t bytes) -> void* {
        off = (off + 255) & ~(size_t)255;
        void* p = ws + off;
        off += bytes;
        return p;
    };

    _Float16* wt_h = (_Float16*)alloc((size_t)E_ * C_ * 2);
    _Float16* wp_h = (_Float16*)alloc((size_t)E_ * C_ * 2);
    _Float16* wg_h = (_Float16*)alloc((size_t)E_ * C_ * 2);
    _Float16* wo_h = (_Float16*)alloc((size_t)C_ * E_ * 2);
    float* scale   = (float*)alloc((size_t)C_ * 4);
    float* shift   = (float*)alloc((size_t)C_ * 4);
    _Float16* XT   = (_Float16*)alloc((size_t)B_ * N_ * C_ * 2);
    _Float16* XST  = (_Float16*)alloc((size_t)B_ * M_ * C_ * 2);
    _Float16* Th   = (_Float16*)alloc((size_t)B_ * N_ * E_ * 2);
    _Float16* Ph   = (_Float16*)alloc((size_t)B_ * M_ * E_ * 2);
    _Float16* Gb   = (_Float16*)alloc((size_t)B_ * E_ * M_ * 2);
    _Float16* Yt   = (_Float16*)alloc((size_t)B_ * N_ * E_ * 2);
    float*    Sb   = (float*)alloc((size_t)N_ * M_ * 4);
    _Float16* Pb   = (_Float16*)alloc((size_t)N_ * M_ * 2);
    (void)ws_size; (void)in_sizes; (void)n_in; (void)out_size;

    prep_kernel<<<dim3((E_ * C_) / 256), dim3(256), 0, stream>>>(
        w_theta, w_phi, w_g, w_out, b_out, gamma, beta, mean, var,
        wt_h, wp_h, wg_h, wo_h, scale, shift, E_ * C_, C_);

    xt_kernel<<<dim3(N_ / 32, C_ / 32, B_), dim3(32, 8), 0, stream>>>(x, XT);
    pool_kernel<<<dim3(M_ / 32, C_ / 32, B_), dim3(32, 8), 0, stream>>>(x, XST);

    // ThetaT [N,E] = XT[N,C] * wt_h[E,C]^T, bias over cols (e)
    gemm_nt<1, 0><<<dim3(E_ / 128, N_ / 128, B_), dim3(256), 0, stream>>>(
        XT, wt_h, Th, b_theta, nullptr, nullptr, nullptr,
        N_, E_, C_, (long long)N_ * C_, 0, (long long)N_ * E_);

    // PhiT [M,E]
    gemm_nt<1, 0><<<dim3(E_ / 128, (M_ + 127) / 128, B_), dim3(256), 0, stream>>>(
        XST, wp_h, Ph, b_phi, nullptr, nullptr, nullptr,
        M_, E_, C_, (long long)M_ * C_, 0, (long long)M_ * E_);

    // G [E,M], bias over rows (e)
    gemm_nt<2, 0><<<dim3((M_ + 127) / 128, E_ / 128, B_), dim3(256), 0, stream>>>(
        wg_h, XST, Gb, b_g, nullptr, nullptr, nullptr,
        E_, M_, C_, 0, (long long)M_ * C_, (long long)E_ * M_);

    for (int b = 0; b < B_; b++) {
        const _Float16* Thb = Th + (size_t)b * N_ * E_;
        const _Float16* Phb = Ph + (size_t)b * M_ * E_;
        const _Float16* Gbb = Gb + (size_t)b * E_ * M_;
        _Float16* Ytb = Yt + (size_t)b * N_ * E_;

        // S [N,M] fp32 = ThetaT * PhiT^T
        gemm_nt<0, 1><<<dim3((M_ + 127) / 128, N_ / 128, 1), dim3(256), 0, stream>>>(
            Thb, Phb, Sb, nullptr, nullptr, nullptr, nullptr,
            N_, M_, E_, 0, 0, 0);

        softmax_kernel<<<dim3((N_ + 3) / 4), dim3(256), 0, stream>>>(Sb, Pb, N_, M_);

        // YT [N,E] = P[N,M] * G[E,M]^T
        gemm_nt<0, 0><<<dim3(E_ / 128, N_ / 128, 1), dim3(256), 0, stream>>>(
            Pb, Gbb, Ytb, nullptr, nullptr, nullptr, nullptr,
            N_, E_, M_, 0, 0, 0);
    }

    // out [B,C,N] = BN(w_out*Y + b_out) + x
    gemm_nt<0, 2><<<dim3(N_ / 128, C_ / 128, B_), dim3(256), 0, stream>>>(
        wo_h, Yt, out, nullptr, scale, shift, x,
        C_, N_, E_, 0, (long long)N_ * E_, (long long)C_ * N_);
}

// Round 2
// 995.461 us; speedup vs baseline: 1.4905x; 1.4905x over previous
//
#include <hip/hip_runtime.h>
#include <cstddef>

typedef _Float16 f16x8 __attribute__((ext_vector_type(8)));
typedef float f32x4 __attribute__((ext_vector_type(4)));

#define B_ 8
#define C_ 1024
#define T_ 8
#define H_ 28
#define W_ 28
#define E_ 512
#define N_ (T_*H_*W_)          // 6272
#define M_ (T_*(H_/2)*(W_/2))  // 1568

__device__ __forceinline__ void gld16(const _Float16* g, _Float16* l) {
    __builtin_amdgcn_global_load_lds((const __attribute__((address_space(1))) void*)g,
                                     (__attribute__((address_space(3))) void*)l, 16, 0, 0);
}

// ---------------------------------------------------------------------------
// prep: weights fp32->f16, fold BN + b_out into scale/shift
// ---------------------------------------------------------------------------
__global__ void prep_kernel(const float* __restrict__ wt, const float* __restrict__ wp,
                            const float* __restrict__ wg, const float* __restrict__ wo,
                            const float* __restrict__ b_out,
                            const float* __restrict__ gamma, const float* __restrict__ beta,
                            const float* __restrict__ mean, const float* __restrict__ var,
                            _Float16* __restrict__ wt_h, _Float16* __restrict__ wp_h,
                            _Float16* __restrict__ wg_h, _Float16* __restrict__ wo_h,
                            float* __restrict__ scale, float* __restrict__ shift,
                            int nW, int nC)
{
    int i = blockIdx.x * blockDim.x + threadIdx.x;
    if (i < nW) {
        wt_h[i] = (_Float16)wt[i];
        wp_h[i] = (_Float16)wp[i];
        wg_h[i] = (_Float16)wg[i];
        wo_h[i] = (_Float16)wo[i];
    }
    if (i < nC) {
        float sc = gamma[i] * rsqrtf(var[i] + 1e-5f);
        scale[i] = sc;
        shift[i] = (b_out[i] - mean[i]) * sc + beta[i];
    }
}

// ---------------------------------------------------------------------------
// XT[b][n][c] = (f16) x[b][c][n]
// ---------------------------------------------------------------------------
__global__ void xt_kernel(const float* __restrict__ x, _Float16* __restrict__ XT)
{
    __shared__ float sm[32][33];
    int n0 = blockIdx.x * 32, c0 = blockIdx.y * 32, b = blockIdx.z;
    const float* xb = x + (size_t)b * C_ * N_;
    _Float16* xtb = XT + (size_t)b * N_ * C_;
#pragma unroll
    for (int i = 0; i < 4; i++) {
        int c = c0 + threadIdx.y + i * 8;
        sm[threadIdx.y + i * 8][threadIdx.x] = xb[(size_t)c * N_ + n0 + threadIdx.x];
    }
    __syncthreads();
#pragma unroll
    for (int i = 0; i < 4; i++) {
        int n = n0 + threadIdx.y + i * 8;
        xtb[(size_t)n * C_ + c0 + threadIdx.x] = (_Float16)sm[threadIdx.x][threadIdx.y + i * 8];
    }
}

// ---------------------------------------------------------------------------
// XST[b][m][c] = (f16) maxpool_122(x)[b][c][m]
// ---------------------------------------------------------------------------
__global__ void pool_kernel(const float* __restrict__ x, _Float16* __restrict__ XST)
{
    __shared__ float sm[32][33];
    const int H2 = H_ / 2, W2 = W_ / 2, HW = H_ * W_;
    int m0 = blockIdx.x * 32, c0 = blockIdx.y * 32, b = blockIdx.z;
    const float* xb = x + (size_t)b * C_ * T_ * HW;
#pragma unroll
    for (int i = 0; i < 4; i++) {
        int c = c0 + threadIdx.y + i * 8;
        int m = m0 + threadIdx.x;
        int t = m / (H2 * W2);
        int r = m - t * (H2 * W2);
        int h2 = r / W2;
        int w2 = r - h2 * W2;
        const float* p = xb + ((size_t)c * T_ + t) * HW + (h2 * 2) * W_ + w2 * 2;
        float v0 = fmaxf(p[0], p[1]);
        float v1 = fmaxf(p[W_], p[W_ + 1]);
        sm[threadIdx.y + i * 8][threadIdx.x] = fmaxf(v0, v1);
    }
    __syncthreads();
#pragma unroll
    for (int i = 0; i < 4; i++) {
        int m = m0 + threadIdx.y + i * 8;
        XST[((size_t)b * M_ + m) * C_ + c0 + threadIdx.x] = (_Float16)sm[threadIdx.x][threadIdx.y + i * 8];
    }
}

// ---------------------------------------------------------------------------
// in-place softmax over rows of S [rows x M_] f16. One wave per row.
// ---------------------------------------------------------------------------
__global__ void softmax_kernel(_Float16* __restrict__ S, int rows)
{
    int wave = threadIdx.x >> 6, lane = threadIdx.x & 63;
    int row = blockIdx.x * 4 + wave;
    if (row >= rows) return;
    _Float16* s = S + (size_t)row * M_;
    f16x8 v[4];
    bool val[4];
    float mx = -3.4e38f;
#pragma unroll
    for (int it = 0; it < 4; it++) {
        int base = it * 512 + lane * 8;
        val[it] = (base < M_);
        if (val[it]) {
            v[it] = *(const f16x8*)(s + base);
#pragma unroll
            for (int q = 0; q < 8; q++) mx = fmaxf(mx, (float)v[it][q]);
        }
    }
#pragma unroll
    for (int off = 32; off > 0; off >>= 1) mx = fmaxf(mx, __shfl_xor(mx, off, 64));
    float ev[32];
    float sum = 0.f;
#pragma unroll
    for (int it = 0; it < 4; it++) {
        if (val[it]) {
#pragma unroll
            for (int q = 0; q < 8; q++) {
                float e = __expf((float)v[it][q] - mx);
                ev[it * 8 + q] = e;
                sum += e;
            }
        }
    }
#pragma unroll
    for (int off = 32; off > 0; off >>= 1) sum += __shfl_xor(sum, off, 64);
    float inv = 1.f / sum;
#pragma unroll
    for (int it = 0; it < 4; it++) {
        if (val[it]) {
            f16x8 o;
#pragma unroll
            for (int q = 0; q < 8; q++) o[q] = (_Float16)(ev[it * 8 + q] * inv);
            *(f16x8*)(s + it * 512 + lane * 8) = o;
        }
    }
}

// ---------------------------------------------------------------------------
// NT GEMM: C[m,n] = sum_k A[m,k]*B[n,k].  128x128 tile, BK=32, 4 waves.
// global_load_lds width-16 staging (m97 structure), LDS-transpose epilogue.
// BIAS: 0 none, 1 per-col, 2 per-row.  EPI: 0 f16 out, 2 fused BN+residual f32.
// ---------------------------------------------------------------------------
template<int BIAS, int EPI>
__global__ __launch_bounds__(256, 2)
void gemm_nt(const _Float16* __restrict__ A, const _Float16* __restrict__ B,
             void* __restrict__ Cout, const float* __restrict__ bias,
             const float* __restrict__ scale, const float* __restrict__ shift,
             const float* __restrict__ resid,
             int Mdim, int Ndim, int K,
             long long strideA, long long strideB, long long strideC)
{
    __shared__ alignas(16) _Float16 As[128 * 32];  // [row][k] unpadded (global_load_lds layout)
    __shared__ alignas(16) _Float16 Bs[128 * 32];
    __shared__ alignas(16) float eps_[32 * 132];   // epilogue transpose slab

    const int tid = threadIdx.x;
    const int lane = tid & 63;
    const int wave = tid >> 6;
    const int wm = wave >> 1, wn = wave & 1;
    const int lane15 = lane & 15, quad = lane >> 4;

    const int m0 = blockIdx.y * 128;
    const int n0 = blockIdx.x * 128;
    const int bz = blockIdx.z;
    A += (size_t)bz * strideA;
    B += (size_t)bz * strideB;

    // staging: 16B-chunk c -> row = c>>2, kchunk = c&3; wave w owns chunks [w*128, w*128+128)
    const int c0 = wave * 128 + lane;
    const int c1 = c0 + 64;
    const int ar0 = min(m0 + (c0 >> 2), Mdim - 1);
    const int ar1 = min(m0 + (c1 >> 2), Mdim - 1);
    const int br0 = min(n0 + (c0 >> 2), Ndim - 1);
    const int br1 = min(n0 + (c1 >> 2), Ndim - 1);
    const _Float16* ap0 = A + (size_t)ar0 * K + (c0 & 3) * 8;
    const _Float16* ap1 = A + (size_t)ar1 * K + (c1 & 3) * 8;
    const _Float16* bp0 = B + (size_t)br0 * K + (c0 & 3) * 8;
    const _Float16* bp1 = B + (size_t)br1 * K + (c1 & 3) * 8;
    _Float16* lA0 = As + wave * 1024;
    _Float16* lA1 = As + wave * 1024 + 512;
    _Float16* lB0 = Bs + wave * 1024;
    _Float16* lB1 = Bs + wave * 1024 + 512;

    f32x4 acc[4][4];
#pragma unroll
    for (int i = 0; i < 4; i++)
#pragma unroll
        for (int j = 0; j < 4; j++)
            acc[i][j] = (f32x4){0.f, 0.f, 0.f, 0.f};

    for (int k0 = 0; k0 < K; k0 += 32) {
        __syncthreads();
        gld16(ap0 + k0, lA0);
        gld16(ap1 + k0, lA1);
        gld16(bp0 + k0, lB0);
        gld16(bp1 + k0, lB1);
        __syncthreads();

        f16x8 af[4], bf[4];
#pragma unroll
        for (int i = 0; i < 4; i++)
            af[i] = *(const f16x8*)&As[(wm * 64 + i * 16 + lane15) * 32 + quad * 8];
#pragma unroll
        for (int j = 0; j < 4; j++)
            bf[j] = *(const f16x8*)&Bs[(wn * 64 + j * 16 + lane15) * 32 + quad * 8];
#pragma unroll
        for (int i = 0; i < 4; i++)
#pragma unroll
            for (int j = 0; j < 4; j++)
                acc[i][j] = __builtin_amdgcn_mfma_f32_16x16x32_f16(af[i], bf[j], acc[i][j], 0, 0, 0);
    }

    // epilogue: acc D layout col=lane&15, row=quad*4+reg. Stage 32 rows (wm pair)
    // per i-pass into LDS, then coalesced vector I/O.
    const size_t cbase = (size_t)bz * strideC;
#pragma unroll
    for (int i = 0; i < 4; i++) {
        __syncthreads();
#pragma unroll
        for (int j = 0; j < 4; j++) {
            int col = wn * 64 + j * 16 + lane15;
#pragma unroll
            for (int r = 0; r < 4; r++)
                eps_[(wm * 16 + quad * 4 + r) * 132 + col] = acc[i][j][r];
        }
        __syncthreads();
        if (EPI == 2) {
            // full tiles, no masking (dims divide 128)
            int rg = tid >> 5, cc = tid & 31;
#pragma unroll
            for (int r = 0; r < 4; r++) {
                int lr = rg * 4 + r;
                int grow = m0 + (lr >> 4) * 64 + i * 16 + (lr & 15);
                int gcol = n0 + cc * 4;
                size_t idx = cbase + (size_t)grow * Ndim + gcol;
                f32x4 v = *(const f32x4*)&eps_[lr * 132 + cc * 4];
                f32x4 res = *(const f32x4*)&resid[idx];
                float sc = scale[grow], sh = shift[grow];
                f32x4 o;
#pragma unroll
                for (int q = 0; q < 4; q++) o[q] = v[q] * sc + sh + res[q];
                *(f32x4*)&((float*)Cout)[idx] = o;
            }
        } else {
            int rg = tid >> 4, cc8 = tid & 15;
#pragma unroll
            for (int r2 = 0; r2 < 2; r2++) {
                int lr = rg * 2 + r2;
                int grow = m0 + (lr >> 4) * 64 + i * 16 + (lr & 15);
                int gcol = n0 + cc8 * 8;
                if (grow < Mdim && gcol < Ndim) {
                    f16x8 o;
#pragma unroll
                    for (int q = 0; q < 8; q++) {
                        float v2 = eps_[lr * 132 + cc8 * 8 + q];
                        if (BIAS == 1) v2 += bias[gcol + q];
                        if (BIAS == 2) v2 += bias[grow];
                        o[q] = (_Float16)v2;
                    }
                    *(f16x8*)&((_Float16*)Cout)[cbase + (size_t)grow * Ndim + gcol] = o;
                }
            }
        }
    }
}

// ---------------------------------------------------------------------------
extern "C" void kernel_launch(void* const* d_in, const int* in_sizes, int n_in,
                              void* d_out, int out_size, void* d_ws, size_t ws_size,
                              hipStream_t stream)
{
    const float* x       = (const float*)d_in[0];
    const float* w_theta = (const float*)d_in[1];
    const float* b_theta = (const float*)d_in[2];
    const float* w_phi   = (const float*)d_in[3];
    const float* b_phi   = (const float*)d_in[4];
    const float* w_g     = (const float*)d_in[5];
    const float* b_g     = (const float*)d_in[6];
    const float* w_out   = (const float*)d_in[7];
    const float* b_out   = (const float*)d_in[8];
    const float* gamma   = (const float*)d_in[9];
    const float* beta    = (const float*)d_in[10];
    const float* mean    = (const float*)d_in[11];
    const float* var     = (const float*)d_in[12];
    float* out = (float*)d_out;
    (void)in_sizes; (void)n_in; (void)out_size;

    char* ws = (char*)d_ws;
    size_t off = 0;
    auto alloc = [&](size_t bytes) -> void* {
        off = (off + 255) & ~(size_t)255;
        void* p = ws + off;
        off += bytes;
        return p;
    };

    _Float16* wt_h = (_Float16*)alloc((size_t)E_ * C_ * 2);
    _Float16* wp_h = (_Float16*)alloc((size_t)E_ * C_ * 2);
    _Float16* wg_h = (_Float16*)alloc((size_t)E_ * C_ * 2);
    _Float16* wo_h = (_Float16*)alloc((size_t)C_ * E_ * 2);
    float* scale   = (float*)alloc((size_t)C_ * 4);
    float* shift   = (float*)alloc((size_t)C_ * 4);
    _Float16* XT   = (_Float16*)alloc((size_t)B_ * N_ * C_ * 2);
    _Float16* XST  = (_Float16*)alloc((size_t)B_ * M_ * C_ * 2);
    _Float16* Th   = (_Float16*)alloc((size_t)B_ * N_ * E_ * 2);
    _Float16* Ph   = (_Float16*)alloc((size_t)B_ * M_ * E_ * 2);
    _Float16* Gb   = (_Float16*)alloc((size_t)B_ * E_ * M_ * 2);
    _Float16* Yt   = (_Float16*)alloc((size_t)B_ * N_ * E_ * 2);

    // S/P (f16, in-place softmax): all 8 batches if workspace allows
    size_t sz_s_all = (size_t)B_ * N_ * M_ * 2;
    bool batched = ws_size > off + sz_s_all + 65536;
    _Float16* Sall = (_Float16*)alloc(batched ? sz_s_all : (size_t)N_ * M_ * 2);

    prep_kernel<<<dim3((E_ * C_) / 256), dim3(256), 0, stream>>>(
        w_theta, w_phi, w_g, w_out, b_out, gamma, beta, mean, var,
        wt_h, wp_h, wg_h, wo_h, scale, shift, E_ * C_, C_);

    xt_kernel<<<dim3(N_ / 32, C_ / 32, B_), dim3(32, 8), 0, stream>>>(x, XT);
    pool_kernel<<<dim3(M_ / 32, C_ / 32, B_), dim3(32, 8), 0, stream>>>(x, XST);

    // ThetaT [N,E] = XT[N,C] * wt^T, bias per-col
    gemm_nt<1, 0><<<dim3(E_ / 128, N_ / 128, B_), dim3(256), 0, stream>>>(
        XT, wt_h, Th, b_theta, nullptr, nullptr, nullptr,
        N_, E_, C_, (long long)N_ * C_, 0, (long long)N_ * E_);

    // PhiT [M,E]
    gemm_nt<1, 0><<<dim3(E_ / 128, (M_ + 127) / 128, B_), dim3(256), 0, stream>>>(
        XST, wp_h, Ph, b_phi, nullptr, nullptr, nullptr,
        M_, E_, C_, (long long)M_ * C_, 0, (long long)M_ * E_);

    // G [E,M], bias per-row
    gemm_nt<2, 0><<<dim3((M_ + 127) / 128, E_ / 128, B_), dim3(256), 0, stream>>>(
        wg_h, XST, Gb, b_g, nullptr, nullptr, nullptr,
        E_, M_, C_, 0, (long long)M_ * C_, (long long)E_ * M_);

    const int nbz = batched ? B_ : 1;
    for (int b0 = 0; b0 < B_; b0 += nbz) {
        // S [N,M] f16 = ThetaT * PhiT^T
        gemm_nt<0, 0><<<dim3((M_ + 127) / 128, N_ / 128, nbz), dim3(256), 0, stream>>>(
            Th + (size_t)b0 * N_ * E_, Ph + (size_t)b0 * M_ * E_, Sall,
            nullptr, nullptr, nullptr, nullptr,
            N_, M_, E_, (long long)N_ * E_, (long long)M_ * E_, (long long)N_ * M_);

        softmax_kernel<<<dim3((nbz * N_) / 4), dim3(256), 0, stream>>>(Sall, nbz * N_);

        // YT [N,E] = P[N,M] * G[E,M]^T
        gemm_nt<0, 0><<<dim3(E_ / 128, N_ / 128, nbz), dim3(256), 0, stream>>>(
            Sall, Gb + (size_t)b0 * E_ * M_, Yt + (size_t)b0 * N_ * E_,
            nullptr, nullptr, nullptr, nullptr,
            N_, E_, M_, (long long)N_ * M_, (long long)E_ * M_, (long long)N_ * E_);
    }

    // out [B,C,N] = BN(w_out*Y + b_out) + x
    gemm_nt<0, 2><<<dim3(N_ / 128, C_ / 128, B_), dim3(256), 0, stream>>>(
        wo_h, Yt, out, nullptr, scale, shift, x,
        C_, N_, E_, 0, (long long)N_ * E_, (long long)C_ * N_);
}